// Round 18
// baseline (96.950 us; speedup 1.0000x reference)
//
#include <hip/hip_runtime.h>
#include <math.h>

#define NCAPS 8
#define SEQ 200
#define EMB 128
#define CDIM 64
#define NROUNDS 3
#define BPAD 68    // CRITICAL: row base bank-quad = 4l%32 -> 8 consecutive rows hit
                   // 8 DISTINCT quads; column/row-phased reads conflict-free.
#define CPAD 68

typedef __bf16 bf16x8 __attribute__((ext_vector_type(8)));
typedef float f32x4 __attribute__((ext_vector_type(4)));
typedef unsigned short ushort8 __attribute__((ext_vector_type(8)));

__device__ __forceinline__ float4 ld4(const float* p) { return *reinterpret_cast<const float4*>(p); }
__device__ __forceinline__ void st4(float* p, float4 v) { *reinterpret_cast<float4*>(p) = v; }

// One-time: split S (128x64 fp32) into MFMA-fragment-ordered bf16 hi/lo.
// Element (e,d) -> frag fi=(e>>5)*4+(d>>4), lane=((e>>3)&3)*16+(d&15), j=e&7.
__global__ void split_S_kernel(const float* __restrict__ S, unsigned short* __restrict__ wsS) {
  int i = blockIdx.x * 256 + threadIdx.x;
  if (i >= EMB * CDIM) return;
  int e = i >> 6, d = i & 63;
  float v = S[i];
  __bf16 hb = (__bf16)v;
  __bf16 lb = (__bf16)(v - (float)hb);
  int fi = (e >> 5) * 4 + (d >> 4);
  int ln = (((e >> 3) & 3) << 4) + (d & 15);
  int j = e & 7;
  wsS[(fi * 64 + ln) * 8 + j] = __builtin_bit_cast(unsigned short, hb);
  wsS[EMB * CDIM + (fi * 64 + ln) * 8 + j] = __builtin_bit_cast(unsigned short, lb);
}

// Projection GEMM v2 (R16-measured best): S fragments staged in LDS, swapped
// MFMA operands (one st4 per ct), 2 row-tiles per wave (128 rows/block).
__global__ __launch_bounds__(256, 2) void proj_kernel(
    const float* __restrict__ A,
    const unsigned short* __restrict__ SfG,
    float* __restrict__ behG,
    int Mtot)
{
  __shared__ ushort8 sF[2048];   // 32 KB: [0..1023]=hi frags, [1024..2047]=lo
  const int t = threadIdx.x;
  const int lane = t & 63;
  const int w = t >> 6;
  const int fr = lane & 15;     // beh row-in-tile (B-operand col); C col
  const int kg = lane >> 4;     // k-group 0..3; C row-quad
  {
    const ushort8* pf = (const ushort8*)SfG;
    for (int i = t; i < 2048; i += 256) sF[i] = pf[i];
  }
  __syncthreads();

#pragma unroll
  for (int rt = 0; rt < 2; ++rt) {
    const int r0 = blockIdx.x * 128 + (w * 2 + rt) * 16;
    const int row = r0 + fr;
    const bool ok = (row < Mtot);
    const float* arow = A + (size_t)row * EMB + kg * 8;

    bf16x8 aH[4], aL[4];
#pragma unroll
    for (int ks = 0; ks < 4; ++ks) {
      if (ok) {
        float4 u0 = ld4(arow + ks * 32);
        float4 u1 = ld4(arow + ks * 32 + 4);
        float a0 = u0.x, a1 = u0.y, a2 = u0.z, a3 = u0.w;
        float a4 = u1.x, a5 = u1.y, a6 = u1.z, a7 = u1.w;
        bf16x8 h, lo;
        h[0] = (__bf16)a0; h[1] = (__bf16)a1; h[2] = (__bf16)a2; h[3] = (__bf16)a3;
        h[4] = (__bf16)a4; h[5] = (__bf16)a5; h[6] = (__bf16)a6; h[7] = (__bf16)a7;
        lo[0] = (__bf16)(a0 - (float)h[0]); lo[1] = (__bf16)(a1 - (float)h[1]);
        lo[2] = (__bf16)(a2 - (float)h[2]); lo[3] = (__bf16)(a3 - (float)h[3]);
        lo[4] = (__bf16)(a4 - (float)h[4]); lo[5] = (__bf16)(a5 - (float)h[5]);
        lo[6] = (__bf16)(a6 - (float)h[6]); lo[7] = (__bf16)(a7 - (float)h[7]);
        aH[ks] = h; aL[ks] = lo;
      } else {
        bf16x8 z;
#pragma unroll
        for (int j = 0; j < 8; ++j) z[j] = (__bf16)0.f;
        aH[ks] = z; aL[ks] = z;
      }
    }

#pragma unroll
    for (int ct = 0; ct < 4; ++ct) {
      f32x4 acc = {0.f, 0.f, 0.f, 0.f};
#pragma unroll
      for (int ks = 0; ks < 4; ++ks) {
        bf16x8 sH = __builtin_bit_cast(bf16x8, sF[(ks * 4 + ct) * 64 + lane]);
        bf16x8 sL = __builtin_bit_cast(bf16x8, sF[1024 + (ks * 4 + ct) * 64 + lane]);
        // swapped: A-operand = S (rows=d), B-operand = beh (cols=l)
        acc = __builtin_amdgcn_mfma_f32_16x16x32_bf16(sH, aH[ks], acc, 0, 0, 0);
        acc = __builtin_amdgcn_mfma_f32_16x16x32_bf16(sH, aL[ks], acc, 0, 0, 0);
        acc = __builtin_amdgcn_mfma_f32_16x16x32_bf16(sL, aH[ks], acc, 0, 0, 0);
      }
      // D layout: col(lane&15)=l-in-tile, row(kg*4+reg)=d-in-ct-tile
      if (ok)
        st4(&behG[(size_t)row * CDIM + ct * 16 + kg * 4],
            make_float4(acc[0], acc[1], acc[2], acc[3]));
    }
  }
}

// Routing: one sample per 512-thread block. Phase B l-partitioned; Phase D
// NEW (R18): lane=(k,dg) d-sliced dot with hoisted caps regs + shfl reduce —
// ~8x fewer LDS issue slots than the per-(k,l) 16-chunk walk.
__global__ __launch_bounds__(512, 4) void route_kernel(
    const float* __restrict__ behG,            // [B][200][64]
    const unsigned char* __restrict__ maskraw, // bool/int32/float32 (detected)
    const float* __restrict__ B0,              // [8][200]
    float* __restrict__ out)                   // [B][8][64]
{
  __shared__ float sBeh[SEQ][BPAD];        // 54.4 KB
  __shared__ float sB[NCAPS][SEQ];         // 6.4 KB
  __shared__ float sWt[SEQ][NCAPS];        // 6.4 KB  (l-major: Phase B broadcasts rows)
  __shared__ float sCaps[NCAPS][CPAD];     // 2.2 KB
  __shared__ float sPart[4][NCAPS][CDIM];  // 8.0 KB
  __shared__ float sMask[SEQ];             // 0.8 KB
  __shared__ int sFlagA, sFlagB;
  // total ~78.1 KB -> 2 blocks/CU

  const int b = blockIdx.x;
  const int t = threadIdx.x;
  const int lane = t & 63;
  const int w = t >> 6;

  // ---- detect mask dtype over first 1KB ----
  if (t == 0) { sFlagA = 0; sFlagB = 0; }
  __syncthreads();
  for (int i = t; i < 1024; i += 512) {
    unsigned char v = maskraw[i];
    if (v != 0) {
      int m = i & 3;
      if (m == 1) atomicOr(&sFlagA, 1);
      else if (m >= 2) atomicOr(&sFlagB, 1);
    }
  }
  __syncthreads();
  const int mode = sFlagA ? 1 : (sFlagB ? 2 : 0);  // 1=bytes, 2=float32, 0=int32

  // ---- load mask, B0, and stage beh from ws ----
  if (mode == 1) {
    for (int i = t; i < SEQ; i += 512)
      sMask[i] = maskraw[(size_t)b * SEQ + i] ? 1.0f : 0.0f;
  } else if (mode == 2) {
    const float* mf = (const float*)maskraw;
    for (int i = t; i < SEQ; i += 512)
      sMask[i] = (mf[(size_t)b * SEQ + i] != 0.0f) ? 1.0f : 0.0f;
  } else {
    const int* mi = (const int*)maskraw;
    for (int i = t; i < SEQ; i += 512)
      sMask[i] = mi[(size_t)b * SEQ + i] ? 1.0f : 0.0f;
  }
  for (int i = t; i < NCAPS * SEQ; i += 512)
    (&sB[0][0])[i] = B0[i];
  for (int i = t; i < SEQ * 16; i += 512) {
    int l = i >> 4, d4 = (i & 15) * 4;
    st4(&sBeh[l][d4], ld4(behG + ((size_t)b * SEQ + l) * CDIM + d4));
  }
  __syncthreads();

  // ---- routing rounds ----
  for (int round = 0; round < NROUNDS; ++round) {
    // Phase A: masked softmax; wave w owns capsule k=w; writes TRANSPOSED sWt[l][k].
    {
      const int k = w;
      float v0 = sB[k][lane],       f0 = sMask[lane];
      float v1 = sB[k][lane + 64],  f1 = sMask[lane + 64];
      float v2 = sB[k][lane + 128], f2 = sMask[lane + 128];
      float v3 = 0.f, f3 = 0.f;
      if (lane < SEQ - 192) { v3 = sB[k][lane + 192]; f3 = sMask[lane + 192]; }
      float m = -3.402823466e38f;
      if (f0 > 0.f) m = fmaxf(m, v0);
      if (f1 > 0.f) m = fmaxf(m, v1);
      if (f2 > 0.f) m = fmaxf(m, v2);
      if (f3 > 0.f) m = fmaxf(m, v3);
#pragma unroll
      for (int off = 32; off >= 1; off >>= 1) m = fmaxf(m, __shfl_xor(m, off));
      float e0 = (f0 > 0.f) ? __expf(v0 - m) : 0.f;
      float e1 = (f1 > 0.f) ? __expf(v1 - m) : 0.f;
      float e2 = (f2 > 0.f) ? __expf(v2 - m) : 0.f;
      float e3 = (f3 > 0.f) ? __expf(v3 - m) : 0.f;
      float s = ((e0 + e1) + (e2 + e3));
#pragma unroll
      for (int off = 32; off >= 1; off >>= 1) s += __shfl_xor(s, off);
      float inv = (s > 0.f) ? (1.0f / s) : 0.f;
      sWt[lane][k] = e0 * inv;
      sWt[lane + 64][k] = e1 * inv;
      sWt[lane + 128][k] = e2 * inv;
      if (lane < SEQ - 192) sWt[lane + 192][k] = e3 * inv;
    }
    __syncthreads();

    // Phase B (l-partitioned): wave w scans l = w+8i (25 rows) for ALL 8 caps.
    float vcap;
    {
      float p0 = 0.f, p1 = 0.f, p2 = 0.f, p3 = 0.f;
      float p4 = 0.f, p5 = 0.f, p6 = 0.f, p7 = 0.f;
      for (int i = 0; i < 25; ++i) {
        const int l = w + 8 * i;
        float bv = sBeh[l][lane];
        float4 wa = ld4(&sWt[l][0]);
        float4 wb = ld4(&sWt[l][4]);
        p0 = fmaf(wa.x, bv, p0); p1 = fmaf(wa.y, bv, p1);
        p2 = fmaf(wa.z, bv, p2); p3 = fmaf(wa.w, bv, p3);
        p4 = fmaf(wb.x, bv, p4); p5 = fmaf(wb.y, bv, p5);
        p6 = fmaf(wb.z, bv, p6); p7 = fmaf(wb.w, bv, p7);
      }
      if (w < 4) {
        sPart[w][0][lane] = p0; sPart[w][1][lane] = p1;
        sPart[w][2][lane] = p2; sPart[w][3][lane] = p3;
        sPart[w][4][lane] = p4; sPart[w][5][lane] = p5;
        sPart[w][6][lane] = p6; sPart[w][7][lane] = p7;
      }
      __syncthreads();
      if (w >= 4) {
        const int u = w - 4;
        sPart[u][0][lane] += p0; sPart[u][1][lane] += p1;
        sPart[u][2][lane] += p2; sPart[u][3][lane] += p3;
        sPart[u][4][lane] += p4; sPart[u][5][lane] += p5;
        sPart[u][6][lane] += p6; sPart[u][7][lane] += p7;
      }
      __syncthreads();
      vcap = (sPart[0][w][lane] + sPart[1][w][lane]) +
             (sPart[2][w][lane] + sPart[3][w][lane]);
    }

    // Phase C: squash in-wave
    {
      float q = vcap * vcap;
#pragma unroll
      for (int off = 32; off >= 1; off >>= 1) q += __shfl_xor(q, off);
      float n = sqrtf(q);
      float f = (q > 0.f) ? (q / ((1.0f + q) * n)) : 0.f;
      vcap *= f;
      sCaps[w][lane] = vcap;
      if (round == NROUNDS - 1)
        out[((size_t)b * NCAPS + w) * CDIM + lane] = vcap;
    }
    __syncthreads();

    // Phase D (R18): lane = (k = lane>>3, dg = lane&7). Each lane holds the
    // caps d-slice [dg*8, dg*8+8) in 2 regs (round-constant, hoisted). Per l:
    // 2 b128 beh reads (2-way aliased = free), 8 fma, 3-shfl dg-reduce,
    // lane dg==0 does the sB RMW. Wave w owns l = w+8i (same (k,l) cover).
    if (round < NROUNDS - 1) {
      const int k8 = lane >> 3;
      const int dg = lane & 7;
      float4 c0 = ld4(&sCaps[k8][dg * 8]);
      float4 c1 = ld4(&sCaps[k8][dg * 8 + 4]);
      for (int i = 0; i < 25; ++i) {
        const int l = w + 8 * i;
        float4 b0 = ld4(&sBeh[l][dg * 8]);
        float4 b1 = ld4(&sBeh[l][dg * 8 + 4]);
        float p = ((c0.x * b0.x + c0.y * b0.y) + (c0.z * b0.z + c0.w * b0.w)) +
                  ((c1.x * b1.x + c1.y * b1.y) + (c1.z * b1.z + c1.w * b1.w));
        p += __shfl_xor(p, 1);
        p += __shfl_xor(p, 2);
        p += __shfl_xor(p, 4);
        if (dg == 0) sB[k8][l] += p;
      }
    }
    __syncthreads();
  }
}

// Fallback (ws too small): fused single-sample kernel (R7 structure).
__global__ __launch_bounds__(512, 2) void mie1_kernel(
    const float* __restrict__ behaviors,
    const unsigned char* __restrict__ maskraw,
    const float* __restrict__ S,
    const float* __restrict__ B0,
    float* __restrict__ out)
{
  __shared__ float sBeh[SEQ][68];
  __shared__ float sB[NCAPS][SEQ];
  __shared__ float sW[NCAPS][SEQ];
  __shared__ float sCaps[NCAPS][CPAD];
  __shared__ float sMask[SEQ];
  __shared__ int sFlagA, sFlagB;
  __shared__ ushort8 sSfH[16 * 64];
  __shared__ ushort8 sSfL[16 * 64];

  const int b = blockIdx.x;
  const int t = threadIdx.x;
  const int lane = t & 63;
  const int w = t >> 6;

  if (t == 0) { sFlagA = 0; sFlagB = 0; }
  __syncthreads();
  for (int i = t; i < 1024; i += 512) {
    unsigned char v = maskraw[i];
    if (v != 0) {
      int m = i & 3;
      if (m == 1) atomicOr(&sFlagA, 1);
      else if (m >= 2) atomicOr(&sFlagB, 1);
    }
  }
  __syncthreads();
  const int mode = sFlagA ? 1 : (sFlagB ? 2 : 0);

  if (mode == 1) {
    for (int i = t; i < SEQ; i += 512)
      sMask[i] = maskraw[(size_t)b * SEQ + i] ? 1.0f : 0.0f;
  } else if (mode == 2) {
    const float* mf = (const float*)maskraw;
    for (int i = t; i < SEQ; i += 512)
      sMask[i] = (mf[(size_t)b * SEQ + i] != 0.0f) ? 1.0f : 0.0f;
  } else {
    const int* mi = (const int*)maskraw;
    for (int i = t; i < SEQ; i += 512)
      sMask[i] = mi[(size_t)b * SEQ + i] ? 1.0f : 0.0f;
  }
  for (int i = t; i < NCAPS * SEQ; i += 512)
    (&sB[0][0])[i] = B0[i];
  for (int i = t; i < EMB * CDIM; i += 512) {
    int e = i >> 6, d = i & 63;
    float v = S[i];
    __bf16 hb = (__bf16)v;
    __bf16 lb = (__bf16)(v - (float)hb);
    int fi = (e >> 5) * 4 + (d >> 4);
    int ln = (((e >> 3) & 3) << 4) + (d & 15);
    int j = e & 7;
    ((unsigned short*)&sSfH[fi * 64 + ln])[j] = __builtin_bit_cast(unsigned short, hb);
    ((unsigned short*)&sSfL[fi * 64 + ln])[j] = __builtin_bit_cast(unsigned short, lb);
  }
  __syncthreads();

  {
    const int fr = lane & 15;
    const int kg = lane >> 4;
    for (int rt = w; rt < 13; rt += 8) {
      const int r0 = rt * 16;
      const int row = r0 + fr;
      const float* arow = behaviors + ((size_t)b * SEQ + row) * EMB + kg * 8;
      f32x4 acc[4];
#pragma unroll
      for (int ct = 0; ct < 4; ++ct) acc[ct] = (f32x4){0.f, 0.f, 0.f, 0.f};
#pragma unroll
      for (int ks = 0; ks < 4; ++ks) {
        bf16x8 aH, aL;
        if (row < SEQ) {
          float4 u0 = ld4(arow + ks * 32);
          float4 u1 = ld4(arow + ks * 32 + 4);
          float a0 = u0.x, a1 = u0.y, a2 = u0.z, a3 = u0.w;
          float a4 = u1.x, a5 = u1.y, a6 = u1.z, a7 = u1.w;
          aH[0] = (__bf16)a0; aH[1] = (__bf16)a1; aH[2] = (__bf16)a2; aH[3] = (__bf16)a3;
          aH[4] = (__bf16)a4; aH[5] = (__bf16)a5; aH[6] = (__bf16)a6; aH[7] = (__bf16)a7;
          aL[0] = (__bf16)(a0 - (float)aH[0]); aL[1] = (__bf16)(a1 - (float)aH[1]);
          aL[2] = (__bf16)(a2 - (float)aH[2]); aL[3] = (__bf16)(a3 - (float)aH[3]);
          aL[4] = (__bf16)(a4 - (float)aH[4]); aL[5] = (__bf16)(a5 - (float)aH[5]);
          aL[6] = (__bf16)(a6 - (float)aH[6]); aL[7] = (__bf16)(a7 - (float)aH[7]);
        } else {
#pragma unroll
          for (int j = 0; j < 8; ++j) { aH[j] = (__bf16)0.f; aL[j] = (__bf16)0.f; }
        }
#pragma unroll
        for (int ct = 0; ct < 4; ++ct) {
          bf16x8 sH = __builtin_bit_cast(bf16x8, sSfH[(ks * 4 + ct) * 64 + lane]);
          bf16x8 sL = __builtin_bit_cast(bf16x8, sSfL[(ks * 4 + ct) * 64 + lane]);
          acc[ct] = __builtin_amdgcn_mfma_f32_16x16x32_bf16(aH, sH, acc[ct], 0, 0, 0);
          acc[ct] = __builtin_amdgcn_mfma_f32_16x16x32_bf16(aL, sH, acc[ct], 0, 0, 0);
          acc[ct] = __builtin_amdgcn_mfma_f32_16x16x32_bf16(aH, sL, acc[ct], 0, 0, 0);
        }
      }
#pragma unroll
      for (int ct = 0; ct < 4; ++ct) {
#pragma unroll
        for (int reg = 0; reg < 4; ++reg) {
          int orow = r0 + kg * 4 + reg;
          if (orow < SEQ) sBeh[orow][ct * 16 + fr] = acc[ct][reg];
        }
      }
    }
  }
  __syncthreads();

  for (int round = 0; round < NROUNDS; ++round) {
    {
      const int k = w;
      float v0 = sB[k][lane],       f0 = sMask[lane];
      float v1 = sB[k][lane + 64],  f1 = sMask[lane + 64];
      float v2 = sB[k][lane + 128], f2 = sMask[lane + 128];
      float v3 = 0.f, f3 = 0.f;
      if (lane < SEQ - 192) { v3 = sB[k][lane + 192]; f3 = sMask[lane + 192]; }
      float m = -3.402823466e38f;
      if (f0 > 0.f) m = fmaxf(m, v0);
      if (f1 > 0.f) m = fmaxf(m, v1);
      if (f2 > 0.f) m = fmaxf(m, v2);
      if (f3 > 0.f) m = fmaxf(m, v3);
#pragma unroll
      for (int off = 32; off >= 1; off >>= 1) m = fmaxf(m, __shfl_xor(m, off));
      float e0 = (f0 > 0.f) ? __expf(v0 - m) : 0.f;
      float e1 = (f1 > 0.f) ? __expf(v1 - m) : 0.f;
      float e2 = (f2 > 0.f) ? __expf(v2 - m) : 0.f;
      float e3 = (f3 > 0.f) ? __expf(v3 - m) : 0.f;
      float s = ((e0 + e1) + (e2 + e3));
#pragma unroll
      for (int off = 32; off >= 1; off >>= 1) s += __shfl_xor(s, off);
      float inv = (s > 0.f) ? (1.0f / s) : 0.f;
      sW[k][lane] = e0 * inv;
      sW[k][lane + 64] = e1 * inv;
      sW[k][lane + 128] = e2 * inv;
      if (lane < SEQ - 192) sW[k][lane + 192] = e3 * inv;
    }
    __syncthreads();
    {
      float a0 = 0.f, a1 = 0.f, a2 = 0.f, a3 = 0.f;
#pragma unroll 2
      for (int l = 0; l < SEQ; l += 4) {
        a0 = fmaf(sW[w][l + 0], sBeh[l + 0][lane], a0);
        a1 = fmaf(sW[w][l + 1], sBeh[l + 1][lane], a1);
        a2 = fmaf(sW[w][l + 2], sBeh[l + 2][lane], a2);
        a3 = fmaf(sW[w][l + 3], sBeh[l + 3][lane], a3);
      }
      float v = (a0 + a1) + (a2 + a3);
      float q = v * v;
#pragma unroll
      for (int off = 32; off >= 1; off >>= 1) q += __shfl_xor(q, off);
      float n = sqrtf(q);
      float f = (q > 0.f) ? (q / ((1.0f + q) * n)) : 0.f;
      v *= f;
      sCaps[w][lane] = v;
      if (round == NROUNDS - 1)
        out[((size_t)b * NCAPS + w) * CDIM + lane] = v;
    }
    __syncthreads();
    if (round < NROUNDS - 1) {
      const int k = t & 7;
      for (int oi = t; oi < NCAPS * SEQ; oi += 512) {
        int l = oi >> 3;
        float px = 0.f, py = 0.f, pz = 0.f, pw = 0.f;
#pragma unroll 4
        for (int i = 0; i < 16; ++i) {
          float4 cp = ld4(&sCaps[k][i * 4]);
          float4 b4 = ld4(&sBeh[l][i * 4]);
          px = fmaf(cp.x, b4.x, px);
          py = fmaf(cp.y, b4.y, py);
          pz = fmaf(cp.z, b4.z, pz);
          pw = fmaf(cp.w, b4.w, pw);
        }
        sB[k][l] += (px + py) + (pz + pw);
      }
    }
    __syncthreads();
  }
}

extern "C" void kernel_launch(void* const* d_in, const int* in_sizes, int n_in,
                              void* d_out, int out_size, void* d_ws, size_t ws_size,
                              hipStream_t stream) {
  const float* behaviors = (const float*)d_in[0];
  const unsigned char* maskraw = (const unsigned char*)d_in[1];
  const float* S = (const float*)d_in[2];
  const float* B0 = (const float*)d_in[3];
  float* out = (float*)d_out;
  const int B = in_sizes[0] / (SEQ * EMB);
  const int Mtot = B * SEQ;
  const size_t sfrag_bytes = (size_t)2 * EMB * CDIM * sizeof(unsigned short); // 32 KB
  const size_t beh_bytes = (size_t)Mtot * CDIM * sizeof(float);               // ~52.4 MB
  if (ws_size >= sfrag_bytes + beh_bytes) {
    unsigned short* wsS = (unsigned short*)d_ws;
    float* behG = (float*)((char*)d_ws + sfrag_bytes);
    split_S_kernel<<<dim3((EMB * CDIM + 255) / 256), dim3(256), 0, stream>>>(S, wsS);
    proj_kernel<<<dim3((Mtot + 127) / 128), dim3(256), 0, stream>>>(behaviors, wsS, behG, Mtot);
    route_kernel<<<dim3(B), dim3(512), 0, stream>>>(behG, maskraw, B0, out);
  } else {
    mie1_kernel<<<dim3(B), dim3(512), 0, stream>>>(behaviors, maskraw, S, B0, out);
  }
}

// Round 19
// 82.350 us; speedup vs baseline: 1.1773x; 1.1773x over previous
//
#include <hip/hip_runtime.h>
#include <math.h>

#define NCAPS 8
#define SEQ 200
#define EMB 128
#define CDIM 64
#define NROUNDS 3
#define BPAD 68    // CRITICAL: row base bank-quad = 4l%32 -> 8 consecutive rows hit
                   // 8 DISTINCT quads; Phase D's 8-row column b128 reads conflict-free.
#define CPAD 68

typedef __bf16 bf16x8 __attribute__((ext_vector_type(8)));
typedef float f32x4 __attribute__((ext_vector_type(4)));
typedef unsigned short ushort8 __attribute__((ext_vector_type(8)));
typedef unsigned short ushort4v __attribute__((ext_vector_type(4)));

__device__ __forceinline__ float4 ld4(const float* p) { return *reinterpret_cast<const float4*>(p); }
__device__ __forceinline__ void st4(float* p, float4 v) { *reinterpret_cast<float4*>(p) = v; }
__device__ __forceinline__ float bf2f(unsigned short b) {
  unsigned u = ((unsigned)b) << 16;
  return __builtin_bit_cast(float, u);
}

// One-time: split S (128x64 fp32) into MFMA-fragment-ordered bf16 hi/lo.
// Element (e,d) -> frag fi=(e>>5)*4+(d>>4), lane=((e>>3)&3)*16+(d&15), j=e&7.
__global__ void split_S_kernel(const float* __restrict__ S, unsigned short* __restrict__ wsS) {
  int i = blockIdx.x * 256 + threadIdx.x;
  if (i >= EMB * CDIM) return;
  int e = i >> 6, d = i & 63;
  float v = S[i];
  __bf16 hb = (__bf16)v;
  __bf16 lb = (__bf16)(v - (float)hb);
  int fi = (e >> 5) * 4 + (d >> 4);
  int ln = (((e >> 3) & 3) << 4) + (d & 15);
  int j = e & 7;
  wsS[(fi * 64 + ln) * 8 + j] = __builtin_bit_cast(unsigned short, hb);
  wsS[EMB * CDIM + (fi * 64 + ln) * 8 + j] = __builtin_bit_cast(unsigned short, lb);
}

// Projection GEMM v2 (R16-measured best) with bf16 OUTPUT (R19):
// S fragments staged in LDS, swapped MFMA operands, 2 row-tiles per wave.
// Output behG16[row][64] bf16 -> write traffic halves (52->26 MB).
__global__ __launch_bounds__(256, 2) void proj_kernel(
    const float* __restrict__ A,
    const unsigned short* __restrict__ SfG,
    unsigned short* __restrict__ behG16,
    int Mtot)
{
  __shared__ ushort8 sF[2048];   // 32 KB: [0..1023]=hi frags, [1024..2047]=lo
  const int t = threadIdx.x;
  const int lane = t & 63;
  const int w = t >> 6;
  const int fr = lane & 15;     // beh row-in-tile (B-operand col); C col
  const int kg = lane >> 4;     // k-group 0..3; C row-quad
  {
    const ushort8* pf = (const ushort8*)SfG;
    for (int i = t; i < 2048; i += 256) sF[i] = pf[i];
  }
  __syncthreads();

#pragma unroll
  for (int rt = 0; rt < 2; ++rt) {
    const int r0 = blockIdx.x * 128 + (w * 2 + rt) * 16;
    const int row = r0 + fr;
    const bool ok = (row < Mtot);
    const float* arow = A + (size_t)row * EMB + kg * 8;

    bf16x8 aH[4], aL[4];
#pragma unroll
    for (int ks = 0; ks < 4; ++ks) {
      if (ok) {
        float4 u0 = ld4(arow + ks * 32);
        float4 u1 = ld4(arow + ks * 32 + 4);
        float a0 = u0.x, a1 = u0.y, a2 = u0.z, a3 = u0.w;
        float a4 = u1.x, a5 = u1.y, a6 = u1.z, a7 = u1.w;
        bf16x8 h, lo;
        h[0] = (__bf16)a0; h[1] = (__bf16)a1; h[2] = (__bf16)a2; h[3] = (__bf16)a3;
        h[4] = (__bf16)a4; h[5] = (__bf16)a5; h[6] = (__bf16)a6; h[7] = (__bf16)a7;
        lo[0] = (__bf16)(a0 - (float)h[0]); lo[1] = (__bf16)(a1 - (float)h[1]);
        lo[2] = (__bf16)(a2 - (float)h[2]); lo[3] = (__bf16)(a3 - (float)h[3]);
        lo[4] = (__bf16)(a4 - (float)h[4]); lo[5] = (__bf16)(a5 - (float)h[5]);
        lo[6] = (__bf16)(a6 - (float)h[6]); lo[7] = (__bf16)(a7 - (float)h[7]);
        aH[ks] = h; aL[ks] = lo;
      } else {
        bf16x8 z;
#pragma unroll
        for (int j = 0; j < 8; ++j) z[j] = (__bf16)0.f;
        aH[ks] = z; aL[ks] = z;
      }
    }

#pragma unroll
    for (int ct = 0; ct < 4; ++ct) {
      f32x4 acc = {0.f, 0.f, 0.f, 0.f};
#pragma unroll
      for (int ks = 0; ks < 4; ++ks) {
        bf16x8 sH = __builtin_bit_cast(bf16x8, sF[(ks * 4 + ct) * 64 + lane]);
        bf16x8 sL = __builtin_bit_cast(bf16x8, sF[1024 + (ks * 4 + ct) * 64 + lane]);
        // swapped: A-operand = S (rows=d), B-operand = beh (cols=l)
        acc = __builtin_amdgcn_mfma_f32_16x16x32_bf16(sH, aH[ks], acc, 0, 0, 0);
        acc = __builtin_amdgcn_mfma_f32_16x16x32_bf16(sH, aL[ks], acc, 0, 0, 0);
        acc = __builtin_amdgcn_mfma_f32_16x16x32_bf16(sL, aH[ks], acc, 0, 0, 0);
      }
      // D layout: col(lane&15)=l-in-tile, row(kg*4+reg)=d-in-ct-tile
      // -> lane stores 4 consecutive d (bf16) of row (r0+fr): one 8B write.
      if (ok) {
        ushort4v o;
        o[0] = __builtin_bit_cast(unsigned short, (__bf16)acc[0]);
        o[1] = __builtin_bit_cast(unsigned short, (__bf16)acc[1]);
        o[2] = __builtin_bit_cast(unsigned short, (__bf16)acc[2]);
        o[3] = __builtin_bit_cast(unsigned short, (__bf16)acc[3]);
        *reinterpret_cast<ushort4v*>(&behG16[(size_t)row * CDIM + ct * 16 + kg * 4]) = o;
      }
    }
  }
}

// Routing (R13/R16-proven phases, UNCHANGED except bf16 staging read):
// one sample per 512-thread block; Phase B l-partitioned; Phase D streams
// caps from LDS; BPAD=68 keeps all patterns conflict-free.
__global__ __launch_bounds__(512, 4) void route_kernel(
    const unsigned short* __restrict__ behG16, // [B][200][64] bf16
    const unsigned char* __restrict__ maskraw, // bool/int32/float32 (detected)
    const float* __restrict__ B0,              // [8][200]
    float* __restrict__ out)                   // [B][8][64]
{
  __shared__ float sBeh[SEQ][BPAD];        // 54.4 KB (fp32, converted at staging)
  __shared__ float sB[NCAPS][SEQ];         // 6.4 KB
  __shared__ float sWt[SEQ][NCAPS];        // 6.4 KB
  __shared__ float sCaps[NCAPS][CPAD];     // 2.2 KB
  __shared__ float sPart[4][NCAPS][CDIM];  // 8.0 KB
  __shared__ float sMask[SEQ];             // 0.8 KB
  __shared__ int sFlagA, sFlagB;
  // total ~78.1 KB -> 2 blocks/CU

  const int b = blockIdx.x;
  const int t = threadIdx.x;
  const int lane = t & 63;
  const int w = t >> 6;

  // ---- detect mask dtype over first 1KB ----
  if (t == 0) { sFlagA = 0; sFlagB = 0; }
  __syncthreads();
  for (int i = t; i < 1024; i += 512) {
    unsigned char v = maskraw[i];
    if (v != 0) {
      int m = i & 3;
      if (m == 1) atomicOr(&sFlagA, 1);
      else if (m >= 2) atomicOr(&sFlagB, 1);
    }
  }
  __syncthreads();
  const int mode = sFlagA ? 1 : (sFlagB ? 2 : 0);  // 1=bytes, 2=float32, 0=int32

  // ---- load mask, B0, and stage beh (bf16 -> fp32) ----
  if (mode == 1) {
    for (int i = t; i < SEQ; i += 512)
      sMask[i] = maskraw[(size_t)b * SEQ + i] ? 1.0f : 0.0f;
  } else if (mode == 2) {
    const float* mf = (const float*)maskraw;
    for (int i = t; i < SEQ; i += 512)
      sMask[i] = (mf[(size_t)b * SEQ + i] != 0.0f) ? 1.0f : 0.0f;
  } else {
    const int* mi = (const int*)maskraw;
    for (int i = t; i < SEQ; i += 512)
      sMask[i] = mi[(size_t)b * SEQ + i] ? 1.0f : 0.0f;
  }
  for (int i = t; i < NCAPS * SEQ; i += 512)
    (&sB[0][0])[i] = B0[i];
  for (int i = t; i < SEQ * 8; i += 512) {
    int l = i >> 3, d8 = (i & 7) * 8;
    ushort8 u = *reinterpret_cast<const ushort8*>(
        behG16 + ((size_t)b * SEQ + l) * CDIM + d8);
    st4(&sBeh[l][d8], make_float4(bf2f(u[0]), bf2f(u[1]), bf2f(u[2]), bf2f(u[3])));
    st4(&sBeh[l][d8 + 4], make_float4(bf2f(u[4]), bf2f(u[5]), bf2f(u[6]), bf2f(u[7])));
  }
  __syncthreads();

  // ---- routing rounds ----
  for (int round = 0; round < NROUNDS; ++round) {
    // Phase A: masked softmax; wave w owns capsule k=w; writes TRANSPOSED sWt[l][k].
    {
      const int k = w;
      float v0 = sB[k][lane],       f0 = sMask[lane];
      float v1 = sB[k][lane + 64],  f1 = sMask[lane + 64];
      float v2 = sB[k][lane + 128], f2 = sMask[lane + 128];
      float v3 = 0.f, f3 = 0.f;
      if (lane < SEQ - 192) { v3 = sB[k][lane + 192]; f3 = sMask[lane + 192]; }
      float m = -3.402823466e38f;
      if (f0 > 0.f) m = fmaxf(m, v0);
      if (f1 > 0.f) m = fmaxf(m, v1);
      if (f2 > 0.f) m = fmaxf(m, v2);
      if (f3 > 0.f) m = fmaxf(m, v3);
#pragma unroll
      for (int off = 32; off >= 1; off >>= 1) m = fmaxf(m, __shfl_xor(m, off));
      float e0 = (f0 > 0.f) ? __expf(v0 - m) : 0.f;
      float e1 = (f1 > 0.f) ? __expf(v1 - m) : 0.f;
      float e2 = (f2 > 0.f) ? __expf(v2 - m) : 0.f;
      float e3 = (f3 > 0.f) ? __expf(v3 - m) : 0.f;
      float s = ((e0 + e1) + (e2 + e3));
#pragma unroll
      for (int off = 32; off >= 1; off >>= 1) s += __shfl_xor(s, off);
      float inv = (s > 0.f) ? (1.0f / s) : 0.f;
      sWt[lane][k] = e0 * inv;
      sWt[lane + 64][k] = e1 * inv;
      sWt[lane + 128][k] = e2 * inv;
      if (lane < SEQ - 192) sWt[lane + 192][k] = e3 * inv;
    }
    __syncthreads();

    // Phase B (l-partitioned): wave w scans l = w+8i (25 rows) for ALL 8 caps.
    float vcap;
    {
      float p0 = 0.f, p1 = 0.f, p2 = 0.f, p3 = 0.f;
      float p4 = 0.f, p5 = 0.f, p6 = 0.f, p7 = 0.f;
      for (int i = 0; i < 25; ++i) {
        const int l = w + 8 * i;
        float bv = sBeh[l][lane];
        float4 wa = ld4(&sWt[l][0]);
        float4 wb = ld4(&sWt[l][4]);
        p0 = fmaf(wa.x, bv, p0); p1 = fmaf(wa.y, bv, p1);
        p2 = fmaf(wa.z, bv, p2); p3 = fmaf(wa.w, bv, p3);
        p4 = fmaf(wb.x, bv, p4); p5 = fmaf(wb.y, bv, p5);
        p6 = fmaf(wb.z, bv, p6); p7 = fmaf(wb.w, bv, p7);
      }
      if (w < 4) {
        sPart[w][0][lane] = p0; sPart[w][1][lane] = p1;
        sPart[w][2][lane] = p2; sPart[w][3][lane] = p3;
        sPart[w][4][lane] = p4; sPart[w][5][lane] = p5;
        sPart[w][6][lane] = p6; sPart[w][7][lane] = p7;
      }
      __syncthreads();
      if (w >= 4) {
        const int u = w - 4;
        sPart[u][0][lane] += p0; sPart[u][1][lane] += p1;
        sPart[u][2][lane] += p2; sPart[u][3][lane] += p3;
        sPart[u][4][lane] += p4; sPart[u][5][lane] += p5;
        sPart[u][6][lane] += p6; sPart[u][7][lane] += p7;
      }
      __syncthreads();
      vcap = (sPart[0][w][lane] + sPart[1][w][lane]) +
             (sPart[2][w][lane] + sPart[3][w][lane]);
    }

    // Phase C: squash in-wave
    {
      float q = vcap * vcap;
#pragma unroll
      for (int off = 32; off >= 1; off >>= 1) q += __shfl_xor(q, off);
      float n = sqrtf(q);
      float f = (q > 0.f) ? (q / ((1.0f + q) * n)) : 0.f;
      vcap *= f;
      sCaps[w][lane] = vcap;
      if (round == NROUNDS - 1)
        out[((size_t)b * NCAPS + w) * CDIM + lane] = vcap;
    }
    __syncthreads();

    // Phase D (R16-proven): B[k][l] += dot(caps[k], beh[l]); caps streamed.
    if (round < NROUNDS - 1) {
      const int k = t & 7;
      for (int oi = t; oi < NCAPS * SEQ; oi += 512) {
        int l = oi >> 3;
        float px = 0.f, py = 0.f, pz = 0.f, pw = 0.f;
#pragma unroll 4
        for (int i = 0; i < 16; ++i) {
          float4 cp = ld4(&sCaps[k][i * 4]);
          float4 b4 = ld4(&sBeh[l][i * 4]);
          px = fmaf(cp.x, b4.x, px);
          py = fmaf(cp.y, b4.y, py);
          pz = fmaf(cp.z, b4.z, pz);
          pw = fmaf(cp.w, b4.w, pw);
        }
        sB[k][l] += (px + py) + (pz + pw);
      }
    }
    __syncthreads();
  }
}

// Fallback (ws too small): fused single-sample kernel (R7 structure).
__global__ __launch_bounds__(512, 2) void mie1_kernel(
    const float* __restrict__ behaviors,
    const unsigned char* __restrict__ maskraw,
    const float* __restrict__ S,
    const float* __restrict__ B0,
    float* __restrict__ out)
{
  __shared__ float sBeh[SEQ][68];
  __shared__ float sB[NCAPS][SEQ];
  __shared__ float sW[NCAPS][SEQ];
  __shared__ float sCaps[NCAPS][CPAD];
  __shared__ float sMask[SEQ];
  __shared__ int sFlagA, sFlagB;
  __shared__ ushort8 sSfH[16 * 64];
  __shared__ ushort8 sSfL[16 * 64];

  const int b = blockIdx.x;
  const int t = threadIdx.x;
  const int lane = t & 63;
  const int w = t >> 6;

  if (t == 0) { sFlagA = 0; sFlagB = 0; }
  __syncthreads();
  for (int i = t; i < 1024; i += 512) {
    unsigned char v = maskraw[i];
    if (v != 0) {
      int m = i & 3;
      if (m == 1) atomicOr(&sFlagA, 1);
      else if (m >= 2) atomicOr(&sFlagB, 1);
    }
  }
  __syncthreads();
  const int mode = sFlagA ? 1 : (sFlagB ? 2 : 0);

  if (mode == 1) {
    for (int i = t; i < SEQ; i += 512)
      sMask[i] = maskraw[(size_t)b * SEQ + i] ? 1.0f : 0.0f;
  } else if (mode == 2) {
    const float* mf = (const float*)maskraw;
    for (int i = t; i < SEQ; i += 512)
      sMask[i] = (mf[(size_t)b * SEQ + i] != 0.0f) ? 1.0f : 0.0f;
  } else {
    const int* mi = (const int*)maskraw;
    for (int i = t; i < SEQ; i += 512)
      sMask[i] = mi[(size_t)b * SEQ + i] ? 1.0f : 0.0f;
  }
  for (int i = t; i < NCAPS * SEQ; i += 512)
    (&sB[0][0])[i] = B0[i];
  for (int i = t; i < EMB * CDIM; i += 512) {
    int e = i >> 6, d = i & 63;
    float v = S[i];
    __bf16 hb = (__bf16)v;
    __bf16 lb = (__bf16)(v - (float)hb);
    int fi = (e >> 5) * 4 + (d >> 4);
    int ln = (((e >> 3) & 3) << 4) + (d & 15);
    int j = e & 7;
    ((unsigned short*)&sSfH[fi * 64 + ln])[j] = __builtin_bit_cast(unsigned short, hb);
    ((unsigned short*)&sSfL[fi * 64 + ln])[j] = __builtin_bit_cast(unsigned short, lb);
  }
  __syncthreads();

  {
    const int fr = lane & 15;
    const int kg = lane >> 4;
    for (int rt = w; rt < 13; rt += 8) {
      const int r0 = rt * 16;
      const int row = r0 + fr;
      const float* arow = behaviors + ((size_t)b * SEQ + row) * EMB + kg * 8;
      f32x4 acc[4];
#pragma unroll
      for (int ct = 0; ct < 4; ++ct) acc[ct] = (f32x4){0.f, 0.f, 0.f, 0.f};
#pragma unroll
      for (int ks = 0; ks < 4; ++ks) {
        bf16x8 aH, aL;
        if (row < SEQ) {
          float4 u0 = ld4(arow + ks * 32);
          float4 u1 = ld4(arow + ks * 32 + 4);
          float a0 = u0.x, a1 = u0.y, a2 = u0.z, a3 = u0.w;
          float a4 = u1.x, a5 = u1.y, a6 = u1.z, a7 = u1.w;
          aH[0] = (__bf16)a0; aH[1] = (__bf16)a1; aH[2] = (__bf16)a2; aH[3] = (__bf16)a3;
          aH[4] = (__bf16)a4; aH[5] = (__bf16)a5; aH[6] = (__bf16)a6; aH[7] = (__bf16)a7;
          aL[0] = (__bf16)(a0 - (float)aH[0]); aL[1] = (__bf16)(a1 - (float)aH[1]);
          aL[2] = (__bf16)(a2 - (float)aH[2]); aL[3] = (__bf16)(a3 - (float)aH[3]);
          aL[4] = (__bf16)(a4 - (float)aH[4]); aL[5] = (__bf16)(a5 - (float)aH[5]);
          aL[6] = (__bf16)(a6 - (float)aH[6]); aL[7] = (__bf16)(a7 - (float)aH[7]);
        } else {
#pragma unroll
          for (int j = 0; j < 8; ++j) { aH[j] = (__bf16)0.f; aL[j] = (__bf16)0.f; }
        }
#pragma unroll
        for (int ct = 0; ct < 4; ++ct) {
          bf16x8 sH = __builtin_bit_cast(bf16x8, sSfH[(ks * 4 + ct) * 64 + lane]);
          bf16x8 sL = __builtin_bit_cast(bf16x8, sSfL[(ks * 4 + ct) * 64 + lane]);
          acc[ct] = __builtin_amdgcn_mfma_f32_16x16x32_bf16(aH, sH, acc[ct], 0, 0, 0);
          acc[ct] = __builtin_amdgcn_mfma_f32_16x16x32_bf16(aL, sH, acc[ct], 0, 0, 0);
          acc[ct] = __builtin_amdgcn_mfma_f32_16x16x32_bf16(aH, sL, acc[ct], 0, 0, 0);
        }
      }
#pragma unroll
      for (int ct = 0; ct < 4; ++ct) {
#pragma unroll
        for (int reg = 0; reg < 4; ++reg) {
          int orow = r0 + kg * 4 + reg;
          if (orow < SEQ) sBeh[orow][ct * 16 + fr] = acc[ct][reg];
        }
      }
    }
  }
  __syncthreads();

  for (int round = 0; round < NROUNDS; ++round) {
    {
      const int k = w;
      float v0 = sB[k][lane],       f0 = sMask[lane];
      float v1 = sB[k][lane + 64],  f1 = sMask[lane + 64];
      float v2 = sB[k][lane + 128], f2 = sMask[lane + 128];
      float v3 = 0.f, f3 = 0.f;
      if (lane < SEQ - 192) { v3 = sB[k][lane + 192]; f3 = sMask[lane + 192]; }
      float m = -3.402823466e38f;
      if (f0 > 0.f) m = fmaxf(m, v0);
      if (f1 > 0.f) m = fmaxf(m, v1);
      if (f2 > 0.f) m = fmaxf(m, v2);
      if (f3 > 0.f) m = fmaxf(m, v3);
#pragma unroll
      for (int off = 32; off >= 1; off >>= 1) m = fmaxf(m, __shfl_xor(m, off));
      float e0 = (f0 > 0.f) ? __expf(v0 - m) : 0.f;
      float e1 = (f1 > 0.f) ? __expf(v1 - m) : 0.f;
      float e2 = (f2 > 0.f) ? __expf(v2 - m) : 0.f;
      float e3 = (f3 > 0.f) ? __expf(v3 - m) : 0.f;
      float s = ((e0 + e1) + (e2 + e3));
#pragma unroll
      for (int off = 32; off >= 1; off >>= 1) s += __shfl_xor(s, off);
      float inv = (s > 0.f) ? (1.0f / s) : 0.f;
      sW[k][lane] = e0 * inv;
      sW[k][lane + 64] = e1 * inv;
      sW[k][lane + 128] = e2 * inv;
      if (lane < SEQ - 192) sW[k][lane + 192] = e3 * inv;
    }
    __syncthreads();
    {
      float a0 = 0.f, a1 = 0.f, a2 = 0.f, a3 = 0.f;
#pragma unroll 2
      for (int l = 0; l < SEQ; l += 4) {
        a0 = fmaf(sW[w][l + 0], sBeh[l + 0][lane], a0);
        a1 = fmaf(sW[w][l + 1], sBeh[l + 1][lane], a1);
        a2 = fmaf(sW[w][l + 2], sBeh[l + 2][lane], a2);
        a3 = fmaf(sW[w][l + 3], sBeh[l + 3][lane], a3);
      }
      float v = (a0 + a1) + (a2 + a3);
      float q = v * v;
#pragma unroll
      for (int off = 32; off >= 1; off >>= 1) q += __shfl_xor(q, off);
      float n = sqrtf(q);
      float f = (q > 0.f) ? (q / ((1.0f + q) * n)) : 0.f;
      v *= f;
      sCaps[w][lane] = v;
      if (round == NROUNDS - 1)
        out[((size_t)b * NCAPS + w) * CDIM + lane] = v;
    }
    __syncthreads();
    if (round < NROUNDS - 1) {
      const int k = t & 7;
      for (int oi = t; oi < NCAPS * SEQ; oi += 512) {
        int l = oi >> 3;
        float px = 0.f, py = 0.f, pz = 0.f, pw = 0.f;
#pragma unroll 4
        for (int i = 0; i < 16; ++i) {
          float4 cp = ld4(&sCaps[k][i * 4]);
          float4 b4 = ld4(&sBeh[l][i * 4]);
          px = fmaf(cp.x, b4.x, px);
          py = fmaf(cp.y, b4.y, py);
          pz = fmaf(cp.z, b4.z, pz);
          pw = fmaf(cp.w, b4.w, pw);
        }
        sB[k][l] += (px + py) + (pz + pw);
      }
    }
    __syncthreads();
  }
}

extern "C" void kernel_launch(void* const* d_in, const int* in_sizes, int n_in,
                              void* d_out, int out_size, void* d_ws, size_t ws_size,
                              hipStream_t stream) {
  const float* behaviors = (const float*)d_in[0];
  const unsigned char* maskraw = (const unsigned char*)d_in[1];
  const float* S = (const float*)d_in[2];
  const float* B0 = (const float*)d_in[3];
  float* out = (float*)d_out;
  const int B = in_sizes[0] / (SEQ * EMB);
  const int Mtot = B * SEQ;
  const size_t sfrag_bytes = (size_t)2 * EMB * CDIM * sizeof(unsigned short); // 32 KB
  const size_t beh_bytes = (size_t)Mtot * CDIM * sizeof(unsigned short);      // ~26.2 MB
  if (ws_size >= sfrag_bytes + beh_bytes) {
    unsigned short* wsS = (unsigned short*)d_ws;
    unsigned short* behG16 = (unsigned short*)((char*)d_ws + sfrag_bytes);
    split_S_kernel<<<dim3((EMB * CDIM + 255) / 256), dim3(256), 0, stream>>>(S, wsS);
    proj_kernel<<<dim3((Mtot + 127) / 128), dim3(256), 0, stream>>>(behaviors, wsS, behG16, Mtot);
    route_kernel<<<dim3(B), dim3(512), 0, stream>>>(behG16, maskraw, B0, out);
  } else {
    mie1_kernel<<<dim3(B), dim3(512), 0, stream>>>(behaviors, maskraw, S, B0, out);
  }
}

// Round 20
// 74.380 us; speedup vs baseline: 1.3034x; 1.1072x over previous
//
#include <hip/hip_runtime.h>
#include <math.h>

#define NCAPS 8
#define SEQ 200
#define EMB 128
#define CDIM 64
#define NROUNDS 3
#define BPAD 68    // CRITICAL: row base bank-quad = 4l%32 -> conflict-free row/col patterns
#define CPAD 68

typedef __bf16 bf16x8 __attribute__((ext_vector_type(8)));
typedef float f32x4 __attribute__((ext_vector_type(4)));
typedef unsigned short ushort8 __attribute__((ext_vector_type(8)));
typedef unsigned short ushort4v __attribute__((ext_vector_type(4)));

__device__ __forceinline__ float4 ld4(const float* p) { return *reinterpret_cast<const float4*>(p); }
__device__ __forceinline__ void st4(float* p, float4 v) { *reinterpret_cast<float4*>(p) = v; }
__device__ __forceinline__ float bf2f(unsigned short b) {
  unsigned u = ((unsigned)b) << 16;
  return __builtin_bit_cast(float, u);
}
// split a float4-pair into bf16 hi/lo fragments
__device__ __forceinline__ void split8(float4 u0, float4 u1, bf16x8& h, bf16x8& lo) {
  float a[8] = {u0.x, u0.y, u0.z, u0.w, u1.x, u1.y, u1.z, u1.w};
#pragma unroll
  for (int j = 0; j < 8; ++j) {
    h[j] = (__bf16)a[j];
    lo[j] = (__bf16)(a[j] - (float)h[j]);
  }
}

// One-time: split S (128x64 fp32) into MFMA-fragment-ordered bf16 hi/lo.
__global__ void split_S_kernel(const float* __restrict__ S, unsigned short* __restrict__ wsS) {
  int i = blockIdx.x * 256 + threadIdx.x;
  if (i >= EMB * CDIM) return;
  int e = i >> 6, d = i & 63;
  float v = S[i];
  __bf16 hb = (__bf16)v;
  __bf16 lb = (__bf16)(v - (float)hb);
  int fi = (e >> 5) * 4 + (d >> 4);
  int ln = (((e >> 3) & 3) << 4) + (d & 15);
  int j = e & 7;
  wsS[(fi * 64 + ln) * 8 + j] = __builtin_bit_cast(unsigned short, hb);
  wsS[EMB * CDIM + (fi * 64 + ln) * 8 + j] = __builtin_bit_cast(unsigned short, lb);
}

// Projection GEMM v2 + bf16 output (R19-proven): S frags staged in LDS,
// swapped MFMA operands, 2 row-tiles/wave, 8B bf16 C-writes.
__global__ __launch_bounds__(256, 2) void proj_kernel(
    const float* __restrict__ A,
    const unsigned short* __restrict__ SfG,
    unsigned short* __restrict__ behG16,
    int Mtot)
{
  __shared__ ushort8 sF[2048];   // 32 KB
  const int t = threadIdx.x;
  const int lane = t & 63;
  const int w = t >> 6;
  const int fr = lane & 15;
  const int kg = lane >> 4;
  {
    const ushort8* pf = (const ushort8*)SfG;
    for (int i = t; i < 2048; i += 256) sF[i] = pf[i];
  }
  __syncthreads();

#pragma unroll
  for (int rt = 0; rt < 2; ++rt) {
    const int r0 = blockIdx.x * 128 + (w * 2 + rt) * 16;
    const int row = r0 + fr;
    const bool ok = (row < Mtot);
    const float* arow = A + (size_t)row * EMB + kg * 8;

    bf16x8 aH[4], aL[4];
#pragma unroll
    for (int ks = 0; ks < 4; ++ks) {
      if (ok) {
        split8(ld4(arow + ks * 32), ld4(arow + ks * 32 + 4), aH[ks], aL[ks]);
      } else {
        bf16x8 z;
#pragma unroll
        for (int j = 0; j < 8; ++j) z[j] = (__bf16)0.f;
        aH[ks] = z; aL[ks] = z;
      }
    }

#pragma unroll
    for (int ct = 0; ct < 4; ++ct) {
      f32x4 acc = {0.f, 0.f, 0.f, 0.f};
#pragma unroll
      for (int ks = 0; ks < 4; ++ks) {
        bf16x8 sH = __builtin_bit_cast(bf16x8, sF[(ks * 4 + ct) * 64 + lane]);
        bf16x8 sL = __builtin_bit_cast(bf16x8, sF[1024 + (ks * 4 + ct) * 64 + lane]);
        acc = __builtin_amdgcn_mfma_f32_16x16x32_bf16(sH, aH[ks], acc, 0, 0, 0);
        acc = __builtin_amdgcn_mfma_f32_16x16x32_bf16(sH, aL[ks], acc, 0, 0, 0);
        acc = __builtin_amdgcn_mfma_f32_16x16x32_bf16(sL, aH[ks], acc, 0, 0, 0);
      }
      if (ok) {
        ushort4v o;
        o[0] = __builtin_bit_cast(unsigned short, (__bf16)acc[0]);
        o[1] = __builtin_bit_cast(unsigned short, (__bf16)acc[1]);
        o[2] = __builtin_bit_cast(unsigned short, (__bf16)acc[2]);
        o[3] = __builtin_bit_cast(unsigned short, (__bf16)acc[3]);
        *reinterpret_cast<ushort4v*>(&behG16[(size_t)row * CDIM + ct * 16 + kg * 4]) = o;
      }
    }
  }
}

// Routing: R19-proven phases; Phase D REPLACED (R20) with MFMA split-bf16:
// B[8x200] += caps[8x64] @ behT — ~12 b128 + 12 MFMA per wave per round
// instead of ~200 b128.
__global__ __launch_bounds__(512, 4) void route_kernel(
    const unsigned short* __restrict__ behG16, // [B][200][64] bf16
    const unsigned char* __restrict__ maskraw, // bool/int32/float32 (detected)
    const float* __restrict__ B0,              // [8][200]
    float* __restrict__ out)                   // [B][8][64]
{
  __shared__ float sBeh[SEQ][BPAD];        // 54.4 KB (fp32)
  __shared__ float sB[NCAPS][SEQ];         // 6.4 KB
  __shared__ float sWt[SEQ][NCAPS];        // 6.4 KB
  __shared__ float sCaps[NCAPS][CPAD];     // 2.2 KB
  __shared__ float sPart[4][NCAPS][CDIM];  // 8.0 KB
  __shared__ float sMask[SEQ];             // 0.8 KB
  __shared__ int sFlagA, sFlagB;

  const int b = blockIdx.x;
  const int t = threadIdx.x;
  const int lane = t & 63;
  const int w = t >> 6;

  // ---- detect mask dtype over first 1KB ----
  if (t == 0) { sFlagA = 0; sFlagB = 0; }
  __syncthreads();
  for (int i = t; i < 1024; i += 512) {
    unsigned char v = maskraw[i];
    if (v != 0) {
      int m = i & 3;
      if (m == 1) atomicOr(&sFlagA, 1);
      else if (m >= 2) atomicOr(&sFlagB, 1);
    }
  }
  __syncthreads();
  const int mode = sFlagA ? 1 : (sFlagB ? 2 : 0);

  // ---- load mask, B0, and stage beh (bf16 -> fp32) ----
  if (mode == 1) {
    for (int i = t; i < SEQ; i += 512)
      sMask[i] = maskraw[(size_t)b * SEQ + i] ? 1.0f : 0.0f;
  } else if (mode == 2) {
    const float* mf = (const float*)maskraw;
    for (int i = t; i < SEQ; i += 512)
      sMask[i] = (mf[(size_t)b * SEQ + i] != 0.0f) ? 1.0f : 0.0f;
  } else {
    const int* mi = (const int*)maskraw;
    for (int i = t; i < SEQ; i += 512)
      sMask[i] = mi[(size_t)b * SEQ + i] ? 1.0f : 0.0f;
  }
  for (int i = t; i < NCAPS * SEQ; i += 512)
    (&sB[0][0])[i] = B0[i];
  for (int i = t; i < SEQ * 8; i += 512) {
    int l = i >> 3, d8 = (i & 7) * 8;
    ushort8 u = *reinterpret_cast<const ushort8*>(
        behG16 + ((size_t)b * SEQ + l) * CDIM + d8);
    st4(&sBeh[l][d8], make_float4(bf2f(u[0]), bf2f(u[1]), bf2f(u[2]), bf2f(u[3])));
    st4(&sBeh[l][d8 + 4], make_float4(bf2f(u[4]), bf2f(u[5]), bf2f(u[6]), bf2f(u[7])));
  }
  __syncthreads();

  // ---- routing rounds ----
  for (int round = 0; round < NROUNDS; ++round) {
    // Phase A: masked softmax; wave w owns capsule k=w; writes TRANSPOSED sWt[l][k].
    {
      const int k = w;
      float v0 = sB[k][lane],       f0 = sMask[lane];
      float v1 = sB[k][lane + 64],  f1 = sMask[lane + 64];
      float v2 = sB[k][lane + 128], f2 = sMask[lane + 128];
      float v3 = 0.f, f3 = 0.f;
      if (lane < SEQ - 192) { v3 = sB[k][lane + 192]; f3 = sMask[lane + 192]; }
      float m = -3.402823466e38f;
      if (f0 > 0.f) m = fmaxf(m, v0);
      if (f1 > 0.f) m = fmaxf(m, v1);
      if (f2 > 0.f) m = fmaxf(m, v2);
      if (f3 > 0.f) m = fmaxf(m, v3);
#pragma unroll
      for (int off = 32; off >= 1; off >>= 1) m = fmaxf(m, __shfl_xor(m, off));
      float e0 = (f0 > 0.f) ? __expf(v0 - m) : 0.f;
      float e1 = (f1 > 0.f) ? __expf(v1 - m) : 0.f;
      float e2 = (f2 > 0.f) ? __expf(v2 - m) : 0.f;
      float e3 = (f3 > 0.f) ? __expf(v3 - m) : 0.f;
      float s = ((e0 + e1) + (e2 + e3));
#pragma unroll
      for (int off = 32; off >= 1; off >>= 1) s += __shfl_xor(s, off);
      float inv = (s > 0.f) ? (1.0f / s) : 0.f;
      sWt[lane][k] = e0 * inv;
      sWt[lane + 64][k] = e1 * inv;
      sWt[lane + 128][k] = e2 * inv;
      if (lane < SEQ - 192) sWt[lane + 192][k] = e3 * inv;
    }
    __syncthreads();

    // Phase B (l-partitioned): wave w scans l = w+8i (25 rows) for ALL 8 caps.
    float vcap;
    {
      float p0 = 0.f, p1 = 0.f, p2 = 0.f, p3 = 0.f;
      float p4 = 0.f, p5 = 0.f, p6 = 0.f, p7 = 0.f;
      for (int i = 0; i < 25; ++i) {
        const int l = w + 8 * i;
        float bv = sBeh[l][lane];
        float4 wa = ld4(&sWt[l][0]);
        float4 wb = ld4(&sWt[l][4]);
        p0 = fmaf(wa.x, bv, p0); p1 = fmaf(wa.y, bv, p1);
        p2 = fmaf(wa.z, bv, p2); p3 = fmaf(wa.w, bv, p3);
        p4 = fmaf(wb.x, bv, p4); p5 = fmaf(wb.y, bv, p5);
        p6 = fmaf(wb.z, bv, p6); p7 = fmaf(wb.w, bv, p7);
      }
      if (w < 4) {
        sPart[w][0][lane] = p0; sPart[w][1][lane] = p1;
        sPart[w][2][lane] = p2; sPart[w][3][lane] = p3;
        sPart[w][4][lane] = p4; sPart[w][5][lane] = p5;
        sPart[w][6][lane] = p6; sPart[w][7][lane] = p7;
      }
      __syncthreads();
      if (w >= 4) {
        const int u = w - 4;
        sPart[u][0][lane] += p0; sPart[u][1][lane] += p1;
        sPart[u][2][lane] += p2; sPart[u][3][lane] += p3;
        sPart[u][4][lane] += p4; sPart[u][5][lane] += p5;
        sPart[u][6][lane] += p6; sPart[u][7][lane] += p7;
      }
      __syncthreads();
      vcap = (sPart[0][w][lane] + sPart[1][w][lane]) +
             (sPart[2][w][lane] + sPart[3][w][lane]);
    }

    // Phase C: squash in-wave
    {
      float q = vcap * vcap;
#pragma unroll
      for (int off = 32; off >= 1; off >>= 1) q += __shfl_xor(q, off);
      float n = sqrtf(q);
      float f = (q > 0.f) ? (q / ((1.0f + q) * n)) : 0.f;
      vcap *= f;
      sCaps[w][lane] = vcap;
      if (round == NROUNDS - 1)
        out[((size_t)b * NCAPS + w) * CDIM + lane] = vcap;
    }
    __syncthreads();

    // Phase D (R20, MFMA): B[8x200] += caps[8x64] @ behT[64x200].
    // A-frag: row m = lane&15 (= k, zero for k>=8), K-elems d = ks*32+kg*8+j.
    // B-frag: col n = lane&15 (= l-in-tile), K-elems d same -> contiguous
    //         sBeh[l][d..d+8) (2-way bank alias, free).
    // C: col = lane&15 = l-in-tile, row = kg*4+reg = k; write k<8 only.
    if (round < NROUNDS - 1) {
      const int fr = lane & 15;
      const int kg = lane >> 4;
      bf16x8 aH[2], aL[2];
#pragma unroll
      for (int ks = 0; ks < 2; ++ks) {
        if (fr < NCAPS) {
          split8(ld4(&sCaps[fr][ks * 32 + kg * 8]),
                 ld4(&sCaps[fr][ks * 32 + kg * 8 + 4]), aH[ks], aL[ks]);
        } else {
          bf16x8 z;
#pragma unroll
          for (int j = 0; j < 8; ++j) z[j] = (__bf16)0.f;
          aH[ks] = z; aL[ks] = z;
        }
      }
      for (int lt = w; lt < 13; lt += 8) {
        const int l = lt * 16 + fr;
        const int lc = (l < SEQ) ? l : (SEQ - 1);
        f32x4 acc = {0.f, 0.f, 0.f, 0.f};
#pragma unroll
        for (int ks = 0; ks < 2; ++ks) {
          bf16x8 bh, bl;
          split8(ld4(&sBeh[lc][ks * 32 + kg * 8]),
                 ld4(&sBeh[lc][ks * 32 + kg * 8 + 4]), bh, bl);
          acc = __builtin_amdgcn_mfma_f32_16x16x32_bf16(aH[ks], bh, acc, 0, 0, 0);
          acc = __builtin_amdgcn_mfma_f32_16x16x32_bf16(aL[ks], bh, acc, 0, 0, 0);
          acc = __builtin_amdgcn_mfma_f32_16x16x32_bf16(aH[ks], bl, acc, 0, 0, 0);
        }
        if (kg < 2 && l < SEQ) {
#pragma unroll
          for (int reg = 0; reg < 4; ++reg)
            sB[kg * 4 + reg][l] += acc[reg];
        }
      }
    }
    __syncthreads();
  }
}

// Fallback (ws too small): fused single-sample kernel (R7 structure).
__global__ __launch_bounds__(512, 2) void mie1_kernel(
    const float* __restrict__ behaviors,
    const unsigned char* __restrict__ maskraw,
    const float* __restrict__ S,
    const float* __restrict__ B0,
    float* __restrict__ out)
{
  __shared__ float sBeh[SEQ][68];
  __shared__ float sB[NCAPS][SEQ];
  __shared__ float sW[NCAPS][SEQ];
  __shared__ float sCaps[NCAPS][CPAD];
  __shared__ float sMask[SEQ];
  __shared__ int sFlagA, sFlagB;
  __shared__ ushort8 sSfH[16 * 64];
  __shared__ ushort8 sSfL[16 * 64];

  const int b = blockIdx.x;
  const int t = threadIdx.x;
  const int lane = t & 63;
  const int w = t >> 6;

  if (t == 0) { sFlagA = 0; sFlagB = 0; }
  __syncthreads();
  for (int i = t; i < 1024; i += 512) {
    unsigned char v = maskraw[i];
    if (v != 0) {
      int m = i & 3;
      if (m == 1) atomicOr(&sFlagA, 1);
      else if (m >= 2) atomicOr(&sFlagB, 1);
    }
  }
  __syncthreads();
  const int mode = sFlagA ? 1 : (sFlagB ? 2 : 0);

  if (mode == 1) {
    for (int i = t; i < SEQ; i += 512)
      sMask[i] = maskraw[(size_t)b * SEQ + i] ? 1.0f : 0.0f;
  } else if (mode == 2) {
    const float* mf = (const float*)maskraw;
    for (int i = t; i < SEQ; i += 512)
      sMask[i] = (mf[(size_t)b * SEQ + i] != 0.0f) ? 1.0f : 0.0f;
  } else {
    const int* mi = (const int*)maskraw;
    for (int i = t; i < SEQ; i += 512)
      sMask[i] = mi[(size_t)b * SEQ + i] ? 1.0f : 0.0f;
  }
  for (int i = t; i < NCAPS * SEQ; i += 512)
    (&sB[0][0])[i] = B0[i];
  for (int i = t; i < EMB * CDIM; i += 512) {
    int e = i >> 6, d = i & 63;
    float v = S[i];
    __bf16 hb = (__bf16)v;
    __bf16 lb = (__bf16)(v - (float)hb);
    int fi = (e >> 5) * 4 + (d >> 4);
    int ln = (((e >> 3) & 3) << 4) + (d & 15);
    int j = e & 7;
    ((unsigned short*)&sSfH[fi * 64 + ln])[j] = __builtin_bit_cast(unsigned short, hb);
    ((unsigned short*)&sSfL[fi * 64 + ln])[j] = __builtin_bit_cast(unsigned short, lb);
  }
  __syncthreads();

  {
    const int fr = lane & 15;
    const int kg = lane >> 4;
    for (int rt = w; rt < 13; rt += 8) {
      const int r0 = rt * 16;
      const int row = r0 + fr;
      const float* arow = behaviors + ((size_t)b * SEQ + row) * EMB + kg * 8;
      f32x4 acc[4];
#pragma unroll
      for (int ct = 0; ct < 4; ++ct) acc[ct] = (f32x4){0.f, 0.f, 0.f, 0.f};
#pragma unroll
      for (int ks = 0; ks < 4; ++ks) {
        bf16x8 aH, aL;
        if (row < SEQ) {
          split8(ld4(arow + ks * 32), ld4(arow + ks * 32 + 4), aH, aL);
        } else {
#pragma unroll
          for (int j = 0; j < 8; ++j) { aH[j] = (__bf16)0.f; aL[j] = (__bf16)0.f; }
        }
#pragma unroll
        for (int ct = 0; ct < 4; ++ct) {
          bf16x8 sH = __builtin_bit_cast(bf16x8, sSfH[(ks * 4 + ct) * 64 + lane]);
          bf16x8 sL = __builtin_bit_cast(bf16x8, sSfL[(ks * 4 + ct) * 64 + lane]);
          acc[ct] = __builtin_amdgcn_mfma_f32_16x16x32_bf16(aH, sH, acc[ct], 0, 0, 0);
          acc[ct] = __builtin_amdgcn_mfma_f32_16x16x32_bf16(aL, sH, acc[ct], 0, 0, 0);
          acc[ct] = __builtin_amdgcn_mfma_f32_16x16x32_bf16(aH, sL, acc[ct], 0, 0, 0);
        }
      }
#pragma unroll
      for (int ct = 0; ct < 4; ++ct) {
#pragma unroll
        for (int reg = 0; reg < 4; ++reg) {
          int orow = r0 + kg * 4 + reg;
          if (orow < SEQ) sBeh[orow][ct * 16 + fr] = acc[ct][reg];
        }
      }
    }
  }
  __syncthreads();

  for (int round = 0; round < NROUNDS; ++round) {
    {
      const int k = w;
      float v0 = sB[k][lane],       f0 = sMask[lane];
      float v1 = sB[k][lane + 64],  f1 = sMask[lane + 64];
      float v2 = sB[k][lane + 128], f2 = sMask[lane + 128];
      float v3 = 0.f, f3 = 0.f;
      if (lane < SEQ - 192) { v3 = sB[k][lane + 192]; f3 = sMask[lane + 192]; }
      float m = -3.402823466e38f;
      if (f0 > 0.f) m = fmaxf(m, v0);
      if (f1 > 0.f) m = fmaxf(m, v1);
      if (f2 > 0.f) m = fmaxf(m, v2);
      if (f3 > 0.f) m = fmaxf(m, v3);
#pragma unroll
      for (int off = 32; off >= 1; off >>= 1) m = fmaxf(m, __shfl_xor(m, off));
      float e0 = (f0 > 0.f) ? __expf(v0 - m) : 0.f;
      float e1 = (f1 > 0.f) ? __expf(v1 - m) : 0.f;
      float e2 = (f2 > 0.f) ? __expf(v2 - m) : 0.f;
      float e3 = (f3 > 0.f) ? __expf(v3 - m) : 0.f;
      float s = ((e0 + e1) + (e2 + e3));
#pragma unroll
      for (int off = 32; off >= 1; off >>= 1) s += __shfl_xor(s, off);
      float inv = (s > 0.f) ? (1.0f / s) : 0.f;
      sW[k][lane] = e0 * inv;
      sW[k][lane + 64] = e1 * inv;
      sW[k][lane + 128] = e2 * inv;
      if (lane < SEQ - 192) sW[k][lane + 192] = e3 * inv;
    }
    __syncthreads();
    {
      float a0 = 0.f, a1 = 0.f, a2 = 0.f, a3 = 0.f;
#pragma unroll 2
      for (int l = 0; l < SEQ; l += 4) {
        a0 = fmaf(sW[w][l + 0], sBeh[l + 0][lane], a0);
        a1 = fmaf(sW[w][l + 1], sBeh[l + 1][lane], a1);
        a2 = fmaf(sW[w][l + 2], sBeh[l + 2][lane], a2);
        a3 = fmaf(sW[w][l + 3], sBeh[l + 3][lane], a3);
      }
      float v = (a0 + a1) + (a2 + a3);
      float q = v * v;
#pragma unroll
      for (int off = 32; off >= 1; off >>= 1) q += __shfl_xor(q, off);
      float n = sqrtf(q);
      float f = (q > 0.f) ? (q / ((1.0f + q) * n)) : 0.f;
      v *= f;
      sCaps[w][lane] = v;
      if (round == NROUNDS - 1)
        out[((size_t)b * NCAPS + w) * CDIM + lane] = v;
    }
    __syncthreads();
    if (round < NROUNDS - 1) {
      const int k = t & 7;
      for (int oi = t; oi < NCAPS * SEQ; oi += 512) {
        int l = oi >> 3;
        float px = 0.f, py = 0.f, pz = 0.f, pw = 0.f;
#pragma unroll 4
        for (int i = 0; i < 16; ++i) {
          float4 cp = ld4(&sCaps[k][i * 4]);
          float4 b4 = ld4(&sBeh[l][i * 4]);
          px = fmaf(cp.x, b4.x, px);
          py = fmaf(cp.y, b4.y, py);
          pz = fmaf(cp.z, b4.z, pz);
          pw = fmaf(cp.w, b4.w, pw);
        }
        sB[k][l] += (px + py) + (pz + pw);
      }
    }
    __syncthreads();
  }
}

extern "C" void kernel_launch(void* const* d_in, const int* in_sizes, int n_in,
                              void* d_out, int out_size, void* d_ws, size_t ws_size,
                              hipStream_t stream) {
  const float* behaviors = (const float*)d_in[0];
  const unsigned char* maskraw = (const unsigned char*)d_in[1];
  const float* S = (const float*)d_in[2];
  const float* B0 = (const float*)d_in[3];
  float* out = (float*)d_out;
  const int B = in_sizes[0] / (SEQ * EMB);
  const int Mtot = B * SEQ;
  const size_t sfrag_bytes = (size_t)2 * EMB * CDIM * sizeof(unsigned short); // 32 KB
  const size_t beh_bytes = (size_t)Mtot * CDIM * sizeof(unsigned short);      // ~26.2 MB
  if (ws_size >= sfrag_bytes + beh_bytes) {
    unsigned short* wsS = (unsigned short*)d_ws;
    unsigned short* behG16 = (unsigned short*)((char*)d_ws + sfrag_bytes);
    split_S_kernel<<<dim3((EMB * CDIM + 255) / 256), dim3(256), 0, stream>>>(S, wsS);
    proj_kernel<<<dim3((Mtot + 127) / 128), dim3(256), 0, stream>>>(behaviors, wsS, behG16, Mtot);
    route_kernel<<<dim3(B), dim3(512), 0, stream>>>(behG16, maskraw, B0, out);
  } else {
    mie1_kernel<<<dim3(B), dim3(512), 0, stream>>>(behaviors, maskraw, S, B0, out);
  }
}